// Round 1
// baseline (386.276 us; speedup 1.0000x reference)
//
#include <hip/hip_runtime.h>
#include <math.h>

#define N_ 4
#define C_ 64
#define H_ 128
#define W_ 128
#define K_ 3
#define K2_ 9
#define CO_OFF 27   // 3*K2
#define COUT 64
#define TP 16       // pixels per block in main kernel
#define CK 576      // C_*K2_

// ---------------- Kernel 0: transpose w[o][c][kh][kw] -> wT[ck][o] ----------------
__global__ __launch_bounds__(256) void transpose_w_kernel(const float* __restrict__ w,
                                                          float* __restrict__ wT) {
    int i = blockIdx.x * 256 + threadIdx.x;      // over COUT*CK = 36864
    if (i < COUT * CK) {
        int o  = i / CK;
        int ck = i - o * CK;
        wT[ck * COUT + o] = w[i];
    }
}

// ---------------- Kernel 1: offset conv om[n][co][ho][wo] ----------------
// grid: (H*W/256, N*27). co is block-uniform -> w_off loads are scalar.
__global__ __launch_bounds__(256) void offset_conv_kernel(const float* __restrict__ x,
                                                          const float* __restrict__ w_off,
                                                          const float* __restrict__ b_off,
                                                          float* __restrict__ om) {
    int co_n = blockIdx.y;            // n*27 + co
    int n  = co_n / CO_OFF;
    int co = co_n - n * CO_OFF;
    int pix = blockIdx.x * 256 + threadIdx.x;   // 0..H*W-1
    int wo = pix & (W_ - 1);
    int ho = pix >> 7;

    const float* wc0 = w_off + (size_t)co * C_ * K2_;
    const float* xn  = x + (size_t)n * C_ * H_ * W_;

    bool v_ym = (ho - 1) >= 0;
    bool v_yp = (ho + 1) < H_;
    bool v_xm = (wo - 1) >= 0;
    bool v_xp = (wo + 1) < W_;

    float acc = b_off[co];
    for (int c = 0; c < C_; ++c) {
        const float* xc = xn + (size_t)c * H_ * W_ + ho * W_ + wo;
        const float* wc = wc0 + c * K2_;
        float x00 = (v_ym && v_xm) ? xc[-W_ - 1] : 0.f;
        float x01 = (v_ym)         ? xc[-W_]     : 0.f;
        float x02 = (v_ym && v_xp) ? xc[-W_ + 1] : 0.f;
        float x10 = (v_xm)         ? xc[-1]      : 0.f;
        float x11 =                  xc[0];
        float x12 = (v_xp)         ? xc[1]       : 0.f;
        float x20 = (v_yp && v_xm) ? xc[W_ - 1]  : 0.f;
        float x21 = (v_yp)         ? xc[W_]      : 0.f;
        float x22 = (v_yp && v_xp) ? xc[W_ + 1]  : 0.f;
        acc = fmaf(x00, wc[0], acc);
        acc = fmaf(x01, wc[1], acc);
        acc = fmaf(x02, wc[2], acc);
        acc = fmaf(x10, wc[3], acc);
        acc = fmaf(x11, wc[4], acc);
        acc = fmaf(x12, wc[5], acc);
        acc = fmaf(x20, wc[6], acc);
        acc = fmaf(x21, wc[7], acc);
        acc = fmaf(x22, wc[8], acc);
    }
    om[((size_t)co_n * H_ + ho) * W_ + wo] = acc;
}

// ---------------- Kernel 2: deform sample + main conv + bias + relu ----------------
// Block: 256 threads, TP=16 consecutive pixels (one row segment).
__global__ __launch_bounds__(256) void deform_main_kernel(const float* __restrict__ x,
                                                          const float* __restrict__ om,
                                                          const float* __restrict__ wT,
                                                          const float* __restrict__ b,
                                                          float* __restrict__ out) {
    __shared__ float s_samp[TP][CK + 1];      // +1 pad: stride 577 % 32 == 1 -> conflict-free
    __shared__ float s_py[K2_ * TP];
    __shared__ float s_px[K2_ * TP];
    __shared__ float s_m [K2_ * TP];

    int pixbase = blockIdx.x * TP;            // over N*H*W
    int wo0 = pixbase & (W_ - 1);
    int tmp = pixbase >> 7;
    int ho  = tmp & (H_ - 1);
    int n   = tmp >> 7;
    int t = threadIdx.x;

    // ---- pre-phase: per-(k,p) sample coords + mask ----
    if (t < K2_ * TP) {
        int k = t >> 4;              // 0..8
        int p = t & 15;              // 0..15
        int wo = wo0 + p;
        const float* omn = om + ((size_t)n * CO_OFF * H_ + (size_t)ho) * W_ + wo;
        float dy = omn[(size_t)(2 * k)     * H_ * W_];
        float dx = omn[(size_t)(2 * k + 1) * H_ * W_];
        float mm = omn[(size_t)(18 + k)    * H_ * W_];
        float mask = 1.f / (1.f + expf(-mm));
        int kh = k / 3, kw = k - kh * 3;
        s_py[t] = (float)(ho - 1 + kh) + dy;
        s_px[t] = (float)(wo - 1 + kw) + dx;
        s_m [t] = mask;
    }
    __syncthreads();

    // ---- phase 1: bilinear sample into LDS ----
    {
        int p = t & 15;                              // pixel (consecutive wo -> coalesced taps)
        const float* xn = x + (size_t)n * C_ * H_ * W_;
        for (int i = (t >> 4); i < CK; i += 16) {    // 36 iterations
            int c = i / K2_;
            int k = i - c * K2_;
            float py = s_py[k * 16 + p];
            float px = s_px[k * 16 + p];
            float mk = s_m [k * 16 + p];
            float y0f = floorf(py), x0f = floorf(px);
            int y0 = (int)y0f, x0 = (int)x0f;
            float fy = py - y0f, fx = px - x0f;
            const float* xc = xn + (size_t)c * H_ * W_;
            bool vy0 = (unsigned)y0       < (unsigned)H_;
            bool vy1 = (unsigned)(y0 + 1) < (unsigned)H_;
            bool vx0 = (unsigned)x0       < (unsigned)W_;
            bool vx1 = (unsigned)(x0 + 1) < (unsigned)W_;
            const float* r0 = xc + y0 * W_;
            const float* r1 = r0 + W_;
            float v00 = (vy0 && vx0) ? r0[x0]     : 0.f;
            float v01 = (vy0 && vx1) ? r0[x0 + 1] : 0.f;
            float v10 = (vy1 && vx0) ? r1[x0]     : 0.f;
            float v11 = (vy1 && vx1) ? r1[x0 + 1] : 0.f;
            float v = (v00 * (1.f - fx) + v01 * fx) * (1.f - fy)
                    + (v10 * (1.f - fx) + v11 * fx) * fy;
            s_samp[p][i] = v * mk;
        }
    }
    __syncthreads();

    // ---- phase 2: out[o, 4 pixels] = wT . s_samp + b, relu ----
    {
        int psub = t & 3;            // pixel group: pixels psub*4 .. psub*4+3
        int o    = t >> 2;           // 0..63
        float bias = b[o];
        float acc0 = bias, acc1 = bias, acc2 = bias, acc3 = bias;
        int p0 = psub * 4;
        const float* wrow = wT + o;
        for (int ck = 0; ck < CK; ++ck) {
            float wv = wrow[ck * COUT];
            acc0 = fmaf(wv, s_samp[p0 + 0][ck], acc0);
            acc1 = fmaf(wv, s_samp[p0 + 1][ck], acc1);
            acc2 = fmaf(wv, s_samp[p0 + 2][ck], acc2);
            acc3 = fmaf(wv, s_samp[p0 + 3][ck], acc3);
        }
        float* op = out + (((size_t)n * COUT + o) * H_ + ho) * W_ + wo0 + p0;
        op[0] = fmaxf(acc0, 0.f);
        op[1] = fmaxf(acc1, 0.f);
        op[2] = fmaxf(acc2, 0.f);
        op[3] = fmaxf(acc3, 0.f);
    }
}

extern "C" void kernel_launch(void* const* d_in, const int* in_sizes, int n_in,
                              void* d_out, int out_size, void* d_ws, size_t ws_size,
                              hipStream_t stream) {
    const float* x     = (const float*)d_in[0];
    const float* w_off = (const float*)d_in[1];
    const float* b_off = (const float*)d_in[2];
    const float* w     = (const float*)d_in[3];
    const float* b     = (const float*)d_in[4];
    float* out = (float*)d_out;

    // workspace layout
    float* om = (float*)d_ws;                                 // N*27*H*W = 1,769,472 floats
    float* wT = om + (size_t)N_ * CO_OFF * H_ * W_;           // 36,864 floats

    // 0: transpose weights
    transpose_w_kernel<<<(COUT * CK + 255) / 256, 256, 0, stream>>>(w, wT);

    // 1: offset conv
    dim3 g1(H_ * W_ / 256, N_ * CO_OFF);
    offset_conv_kernel<<<g1, 256, 0, stream>>>(x, w_off, b_off, om);

    // 2: deform sample + main conv
    int nblocks = N_ * H_ * W_ / TP;   // 4096
    deform_main_kernel<<<nblocks, 256, 0, stream>>>(x, om, wT, b, out);
}

// Round 2
// 221.927 us; speedup vs baseline: 1.7406x; 1.7406x over previous
//
#include <hip/hip_runtime.h>
#include <math.h>

#define N_ 4
#define C_ 64
#define H_ 128
#define W_ 128
#define K2_ 9
#define COUT 64
#define CK 576          // C_*K2_
#define TP 16           // pixels per block
#define SST 584         // padded LDS row stride (elements); 584*2B=1168B, 16B-aligned rows

typedef __bf16 bf16x8 __attribute__((ext_vector_type(8)));
typedef float floatx4 __attribute__((ext_vector_type(4)));

__device__ __forceinline__ unsigned short f2b(float f) {
    unsigned int u = __builtin_bit_cast(unsigned int, f);
    u = (u + 0x7fffu + ((u >> 16) & 1u)) >> 16;   // RNE
    return (unsigned short)u;
}

// ---------------- prep: fp32 weights -> bf16 (w natural layout; w_off padded to 32 rows) ----
__global__ __launch_bounds__(256) void prep_kernel(const float* __restrict__ w,
                                                   const float* __restrict__ w_off,
                                                   unsigned short* __restrict__ wb,
                                                   unsigned short* __restrict__ w_offb) {
    int i = blockIdx.x * 256 + threadIdx.x;
    if (i < COUT * CK) wb[i] = f2b(w[i]);
    if (i < 32 * CK) {
        int row = i / CK;
        w_offb[i] = (row < 27) ? f2b(w_off[i]) : (unsigned short)0;
    }
}

// ---------------- fused: im2col -> offset-conv MFMA -> coords -> bilinear -> main MFMA ------
__global__ __launch_bounds__(256) void fused_kernel(const float* __restrict__ x,
                                                    const unsigned short* __restrict__ wb,
                                                    const unsigned short* __restrict__ w_offb,
                                                    const float* __restrict__ b_off,
                                                    const float* __restrict__ b,
                                                    float* __restrict__ out) {
    __shared__ __align__(16) unsigned short s_x[TP * SST];   // B^T tile: [p][ck] bf16
    __shared__ float s_om[32 * TP];                          // offset-conv out [co][p]
    __shared__ float s_py[K2_ * TP];
    __shared__ float s_px[K2_ * TP];
    __shared__ float s_m [K2_ * TP];

    int t = threadIdx.x;
    int pixbase = blockIdx.x * TP;            // over N*H*W
    int wo0 = pixbase & (W_ - 1);
    int ho  = (pixbase >> 7) & (H_ - 1);
    int n   = pixbase >> 14;
    const float* xn = x + (size_t)n * C_ * H_ * W_;

    // ---- Phase A: integer-tap im2col (zero-padded) -> s_x bf16 ----
    {
        int p = t & 15;
        int xx0 = wo0 + p - 1;
        for (int i = (t >> 4); i < CK; i += 16) {       // 36 iters
            int c = i / 9;
            int k = i - c * 9;
            int kh = k / 3;
            int kw = k - kh * 3;
            int y  = ho - 1 + kh;
            int xx = xx0 + kw;
            float v = 0.f;
            if ((unsigned)y < (unsigned)H_ && (unsigned)xx < (unsigned)W_)
                v = xn[(size_t)c * (H_ * W_) + y * W_ + xx];
            s_x[p * SST + i] = f2b(v);
        }
    }
    __syncthreads();

    int lane = t & 63;
    int wv   = t >> 6;
    int q    = lane >> 4;
    int col  = lane & 15;

    // ---- Phase B: offset conv via MFMA (waves 0,1 cover co 0..31) ----
    if (wv < 2) {
        floatx4 acc = {0.f, 0.f, 0.f, 0.f};
        const unsigned short* arow = w_offb + (size_t)(16 * wv + col) * CK + q * 8;
        const unsigned short* brow = s_x + col * SST + q * 8;
        for (int k0 = 0; k0 < CK; k0 += 32) {           // 18 MFMAs
            bf16x8 a  = *(const bf16x8*)(arow + k0);
            bf16x8 bb = *(const bf16x8*)(brow + k0);
            acc = __builtin_amdgcn_mfma_f32_16x16x32_bf16(a, bb, acc, 0, 0, 0);
        }
#pragma unroll
        for (int r = 0; r < 4; ++r)
            s_om[(16 * wv + q * 4 + r) * TP + col] = acc[r];
    }
    __syncthreads();

    // ---- coords + sigmoid mask (144 threads) ----
    if (t < K2_ * TP) {
        int k = t >> 4;
        int p = t & 15;
        float dy = s_om[(2 * k)     * TP + p] + b_off[2 * k];
        float dx = s_om[(2 * k + 1) * TP + p] + b_off[2 * k + 1];
        float mm = s_om[(18 + k)    * TP + p] + b_off[18 + k];
        s_m[t] = 1.f / (1.f + expf(-mm));
        int kh = k / 3;
        int kw = k - kh * 3;
        s_py[t] = (float)(ho - 1 + kh) + dy;
        s_px[t] = (float)(wo0 + p - 1 + kw) + dx;
    }
    __syncthreads();

    // ---- Phase C: bilinear sample * mask -> s_x (overwrite, bf16) ----
    {
        int p = t & 15;
        for (int i = (t >> 4); i < CK; i += 16) {       // 36 iters
            int c = i / 9;
            int k = i - c * 9;
            float py = s_py[k * 16 + p];
            float px = s_px[k * 16 + p];
            float mk = s_m [k * 16 + p];
            float y0f = floorf(py), x0f = floorf(px);
            int y0 = (int)y0f, x0 = (int)x0f;
            float fy = py - y0f, fx = px - x0f;
            const float* xc = xn + (size_t)c * (H_ * W_);
            bool vy0 = (unsigned)y0       < (unsigned)H_;
            bool vy1 = (unsigned)(y0 + 1) < (unsigned)H_;
            bool vx0 = (unsigned)x0       < (unsigned)W_;
            bool vx1 = (unsigned)(x0 + 1) < (unsigned)W_;
            const float* r0 = xc + y0 * W_ + x0;
            float v00 = (vy0 && vx0) ? r0[0]      : 0.f;
            float v01 = (vy0 && vx1) ? r0[1]      : 0.f;
            float v10 = (vy1 && vx0) ? r0[W_]     : 0.f;
            float v11 = (vy1 && vx1) ? r0[W_ + 1] : 0.f;
            float v = (v00 * (1.f - fx) + v01 * fx) * (1.f - fy)
                    + (v10 * (1.f - fx) + v11 * fx) * fy;
            s_x[p * SST + i] = f2b(v * mk);
        }
    }
    __syncthreads();

    // ---- Phase D: main conv MFMA (4 waves, o tile = 16*wv) + bias + relu ----
    {
        floatx4 acc = {0.f, 0.f, 0.f, 0.f};
        const unsigned short* arow = wb + (size_t)(16 * wv + col) * CK + q * 8;
        const unsigned short* brow = s_x + col * SST + q * 8;
        for (int k0 = 0; k0 < CK; k0 += 32) {           // 18 MFMAs
            bf16x8 a  = *(const bf16x8*)(arow + k0);
            bf16x8 bb = *(const bf16x8*)(brow + k0);
            acc = __builtin_amdgcn_mfma_f32_16x16x32_bf16(a, bb, acc, 0, 0, 0);
        }
#pragma unroll
        for (int r = 0; r < 4; ++r) {
            int o = 16 * wv + q * 4 + r;
            float v = acc[r] + b[o];
            out[(((size_t)n * COUT + o) * H_ + ho) * W_ + wo0 + col] = fmaxf(v, 0.f);
        }
    }
}

extern "C" void kernel_launch(void* const* d_in, const int* in_sizes, int n_in,
                              void* d_out, int out_size, void* d_ws, size_t ws_size,
                              hipStream_t stream) {
    const float* x     = (const float*)d_in[0];
    const float* w_off = (const float*)d_in[1];
    const float* b_off = (const float*)d_in[2];
    const float* w     = (const float*)d_in[3];
    const float* b     = (const float*)d_in[4];
    float* out = (float*)d_out;

    unsigned short* wb     = (unsigned short*)d_ws;            // 64*576
    unsigned short* w_offb = wb + (size_t)COUT * CK;           // 32*576 (padded)

    prep_kernel<<<(COUT * CK + 255) / 256, 256, 0, stream>>>(w, w_off, wb, w_offb);

    int nblocks = N_ * H_ * W_ / TP;   // 4096
    fused_kernel<<<nblocks, 256, 0, stream>>>(x, wb, w_offb, b_off, b, out);
}